// Round 12
// baseline (77.507 us; speedup 1.0000x reference)
//
#include <hip/hip_runtime.h>
#include <hip/hip_bf16.h>
#include <stdint.h>

// EnergyAttention: out = -sum(logsumexp(SCALE * (Q K^T), axis=-1)) / SCALE
// Q = hs @ qp^T + qb (pre-scaled by SCALE*log2e), K = hs @ kp^T + kb, bf16.

typedef __bf16 bf16_t;
typedef bf16_t bf16x8 __attribute__((ext_vector_type(8)));
typedef float f32x4 __attribute__((ext_vector_type(4)));
typedef float f32x16 __attribute__((ext_vector_type(16)));

#define MFMA16(a,b,c) __builtin_amdgcn_mfma_f32_16x16x32_bf16(a,b,c,0,0,0)
#define MFMA32(a,b,c) __builtin_amdgcn_mfma_f32_32x32x16_bf16(a,b,c,0,0,0)
#define GLL16(g, l) __builtin_amdgcn_global_load_lds(                       \
    (const __attribute__((address_space(1))) void*)(g),                     \
    (__attribute__((address_space(3))) void*)(l), 16, 0, 0)

static constexpr int SEQ = 2048, BATCH = 2, EMBED = 1024, NH = 16, QKD = 64;
static constexpr int M_TOT = BATCH * SEQ;   // 4096
static constexpr int N_TOT = 2 * NH * QKD;  // 2048 (Q cols 0..1023; K-half fragged)
static constexpr float C1 = 0.125f * 1.44269504088896340736f; // SCALE*log2(e)
static constexpr int NBLK_LSE = 512;

// ---- single-launch f32 -> bf16 convert of hs, qp, kp ----
__global__ __launch_bounds__(256) void cvt_kernel(
    const float* __restrict__ hs, const float* __restrict__ qp,
    const float* __restrict__ kp, bf16_t* __restrict__ hsb,
    bf16_t* __restrict__ projb)
{
    int i = blockIdx.x * 256 + threadIdx.x;   // vec8 index, 786432 total
    const float* src; bf16_t* dst;
    if (i < 524288) { src = hs + (size_t)i * 8; dst = hsb + (size_t)i * 8; }
    else {
        int j = i - 524288;
        dst = projb + (size_t)j * 8;
        src = (j < 131072) ? qp + (size_t)j * 8 : kp + (size_t)(j - 131072) * 8;
    }
    f32x4 a = ((const f32x4*)src)[0], b = ((const f32x4*)src)[1];
    bf16x8 r;
    r[0]=(bf16_t)a[0]; r[1]=(bf16_t)a[1]; r[2]=(bf16_t)a[2]; r[3]=(bf16_t)a[3];
    r[4]=(bf16_t)b[0]; r[5]=(bf16_t)b[1]; r[6]=(bf16_t)b[2]; r[7]=(bf16_t)b[3];
    *(bf16x8*)dst = r;
}

// ---- Phase 1: Q/K projection GEMM ----
// 128x128 tile, BK=64, double-buffered LDS, 1 barrier/K-step (round-3 core).
// Epilogue: Q-half (col<1024) -> qkb row-major (pre-scaled by C1);
//           K-half (col>=1024) -> kfrag in MFMA-A-fragment-major layout:
// kfrag[((pair*64+ct)*4+kf)*512 + (g5*32+l31)*8 + e] = K[pair][row=ct*32+l31][kk]
//   where kk = kf*16 + g5*8 + e. (eliminates the separate repack kernel)
__global__ __launch_bounds__(256) void proj_kernel(
    const bf16_t* __restrict__ A, const bf16_t* __restrict__ B,
    const float* __restrict__ qb, const float* __restrict__ kb,
    bf16_t* __restrict__ qkb, bf16_t* __restrict__ kfrag)
{
    __shared__ __align__(16) char sA[2][16384];
    __shared__ __align__(16) char sB[2][16384];
    const int t = threadIdx.x, lane = t & 63, wv = t >> 6;
    const int bid = blockIdx.x;
    const int xcd = bid & 7, idx = bid >> 3;
    const int am0 = (xcd * 4 + (idx >> 4)) * 128;   // M-strip per XCD
    const int bn0 = (idx & 15) * 128;
    const int wr = wv >> 1, wc = wv & 1;
    const int l15 = lane & 15, g = lane >> 4;

    const int srow = wv * 8 + (lane >> 3);
    const int sgr  = (lane & 7) ^ ((lane >> 3) & 7);
    const bf16_t* ga = A + (size_t)(am0 + srow) * EMBED + 8 * sgr;
    const bf16_t* gb = B + (size_t)(bn0 + srow) * EMBED + 8 * sgr;
    const int lbase = wv * 1024;

    f32x4 acc[4][4] = {};

#pragma unroll
    for (int is = 0; is < 4; ++is) {
        GLL16(ga + (size_t)is * 32 * EMBED, &sA[0][lbase + is * 4096]);
        GLL16(gb + (size_t)is * 32 * EMBED, &sB[0][lbase + is * 4096]);
    }
    __syncthreads();

    int cur = 0;
    for (int kk = 0; kk < EMBED; kk += 64) {
        if (kk + 64 < EMBED) {
#pragma unroll
            for (int is = 0; is < 4; ++is) {
                GLL16(ga + kk + 64 + (size_t)is * 32 * EMBED, &sA[cur ^ 1][lbase + is * 4096]);
                GLL16(gb + kk + 64 + (size_t)is * 32 * EMBED, &sB[cur ^ 1][lbase + is * 4096]);
            }
        }
#pragma unroll
        for (int s = 0; s < 2; ++s) {
            bf16x8 af[4], bfv[4];
#pragma unroll
            for (int mt = 0; mt < 4; ++mt) {
                int row = wr * 64 + mt * 16 + l15;
                af[mt] = *(const bf16x8*)&sA[cur][row * 128 + 16 * (((s << 2) | g) ^ (row & 7))];
            }
#pragma unroll
            for (int nt = 0; nt < 4; ++nt) {
                int row = wc * 64 + nt * 16 + l15;
                bfv[nt] = *(const bf16x8*)&sB[cur][row * 128 + 16 * (((s << 2) | g) ^ (row & 7))];
            }
#pragma unroll
            for (int mt = 0; mt < 4; ++mt)
#pragma unroll
                for (int nt = 0; nt < 4; ++nt)
                    acc[mt][nt] = MFMA16(af[mt], bfv[nt], acc[mt][nt]);
        }
        __syncthreads();
        cur ^= 1;
    }

    // epilogue: C/D 16x16 layout col=lane&15, row=(lane>>4)*4+j
#pragma unroll
    for (int nt = 0; nt < 4; ++nt) {
        const int col = bn0 + wc * 64 + nt * 16 + l15;
        if (col < NH * QKD) {
            const float bias = qb[col & 63];
#pragma unroll
            for (int mt = 0; mt < 4; ++mt)
#pragma unroll
                for (int j = 0; j < 4; ++j) {
                    int row = am0 + wr * 64 + mt * 16 + g * 4 + j;
                    qkb[(size_t)row * N_TOT + col] = (bf16_t)((acc[mt][nt][j] + bias) * C1);
                }
        } else {
            const int khcol = col - NH * QKD;
            const int h = khcol >> 6, kcol = khcol & 63;
            const int kf = kcol >> 4, g5k = (kcol >> 3) & 1, e = kcol & 7;
            const float bias = kb[kcol];
#pragma unroll
            for (int mt = 0; mt < 4; ++mt)
#pragma unroll
                for (int j = 0; j < 4; ++j) {
                    int row = am0 + wr * 64 + mt * 16 + g * 4 + j;
                    int b_ = row >> 11, r = row & (SEQ - 1);
                    int pair = b_ * 16 + h, ctk = r >> 5, l31k = r & 31;
                    kfrag[(size_t)((pair * 64 + ctk) * 4 + kf) * 512
                          + (g5k * 32 + l31k) * 8 + e] = (bf16_t)(acc[mt][nt][j] + bias);
                }
        }
    }
}

// ---- Phase 2: per (b,h): rowwise sum of exp2(Q K^T), + fused final reduce ----
// 512 blocks x 128 Q-rows (mt=4: 4 independent MFMA chains/exp groups = ILP).
// Round-3 loop body verbatim (compiler-scheduled). K loads: fully-coalesced
// 1KB bursts from kfrag. Wave wv covers cts [wv*16, wv*16+16).
__global__ __launch_bounds__(256) void lse_kernel(
    const bf16_t* __restrict__ qk, const bf16_t* __restrict__ kfrag,
    float* __restrict__ red, unsigned* __restrict__ cnt, float* __restrict__ out)
{
    __shared__ float rows_s[4][128];
    __shared__ float wsf[4];
    __shared__ int lastflag;
    const int t = threadIdx.x, lane = t & 63, wv = t >> 6;
    const int bid = blockIdx.x;
    const int xcd = bid & 7, idx = bid >> 3;     // idx 0..63
    const int pair = xcd * 4 + (idx >> 4);       // 0..31, 4 pairs per XCD
    const int tile = idx & 15;                   // 0..15
    const int b = pair >> 4, h = pair & 15;
    const int qr0 = tile * 128;
    const int l31 = lane & 31, g5 = lane >> 5;
    const size_t base = (size_t)b * SEQ;

    // Q fragments (B-operand): lane holds Q-row qr0+mt*32+l31, k = kf*16+g5*8
    bf16x8 qf[4][4];
#pragma unroll
    for (int mt = 0; mt < 4; ++mt) {
        const bf16_t* qp_ = qk + (base + qr0 + mt * 32 + l31) * N_TOT + h * QKD + g5 * 8;
#pragma unroll
        for (int kf = 0; kf < 4; ++kf)
            qf[mt][kf] = *(const bf16x8*)(qp_ + kf * 16);
    }

    // K fragments: coalesced; wave wv owns cts wv*16..wv*16+15 (ct step = 2048)
    const bf16_t* kfb = kfrag + ((size_t)(pair * 64 + wv * 16) * 4) * 512 + lane * 8;

    float sume[4] = {0.f, 0.f, 0.f, 0.f};

    bf16x8 kv[4];
#pragma unroll
    for (int kf = 0; kf < 4; ++kf) kv[kf] = *(const bf16x8*)(kfb + kf * 512);

    for (int ct = 0; ct < 16; ++ct) {
        // prefetch next ct's K-frags (clamped on last iter)
        bf16x8 kn[4];
        const bf16_t* kn_p = kfb + (size_t)(ct < 15 ? ct + 1 : 15) * 2048;
#pragma unroll
        for (int kf = 0; kf < 4; ++kf) kn[kf] = *(const bf16x8*)(kn_p + kf * 512);

        // 16 back-to-back MFMA32 (4 independent accumulators), then 64 exp2
        f32x16 sacc[4];
        __builtin_amdgcn_s_setprio(1);
#pragma unroll
        for (int mt = 0; mt < 4; ++mt) {
            f32x16 z = {};
            sacc[mt] = z;
#pragma unroll
            for (int kf = 0; kf < 4; ++kf)
                sacc[mt] = MFMA32(kv[kf], qf[mt][kf], sacc[mt]);
        }
        __builtin_amdgcn_s_setprio(0);
#pragma unroll
        for (int mt = 0; mt < 4; ++mt) {
            float e = 0.f;
#pragma unroll
            for (int j = 0; j < 16; ++j)
                e += __builtin_amdgcn_exp2f(sacc[mt][j]);
            sume[mt] += e;
        }
#pragma unroll
        for (int kf = 0; kf < 4; ++kf) kv[kf] = kn[kf];
    }

    // lane + g5-partner cover all 32 K-rows of each ct for the same Q-row
#pragma unroll
    for (int mt = 0; mt < 4; ++mt) {
        float v = sume[mt] + __shfl_xor(sume[mt], 32);
        if (g5 == 0) rows_s[wv][mt * 32 + l31] = v;
    }
    __syncthreads();

    float lg = 0.f;
    if (t < 128) {
        float tot = rows_s[0][t] + rows_s[1][t] + rows_s[2][t] + rows_s[3][t];
        lg = __builtin_amdgcn_logf(tot);      // v_log_f32 = log2
    }
#pragma unroll
    for (int m = 1; m < 64; m <<= 1) lg += __shfl_xor(lg, m);
    if (lane == 0) wsf[wv] = lg;              // wv0: rows 0..63, wv1: 64..127
    __syncthreads();

    if (t == 0) {
        red[bid] = wsf[0] + wsf[1];
        __threadfence();
        unsigned d = atomicAdd(cnt, 1u);
        lastflag = (d == NBLK_LSE - 1);
    }
    __syncthreads();

    if (lastflag) {                           // last block: final reduce
        __threadfence();
        float s = red[t] + red[t + 256];
#pragma unroll
        for (int m = 1; m < 64; m <<= 1) s += __shfl_xor(s, m);
        if (lane == 0) wsf[wv] = s;
        __syncthreads();
        if (t == 0)
            out[0] = -8.0f * 0.69314718055994530942f * (wsf[0] + wsf[1] + wsf[2] + wsf[3]);
    }
}

extern "C" void kernel_launch(void* const* d_in, const int* in_sizes, int n_in,
                              void* d_out, int out_size, void* d_ws, size_t ws_size,
                              hipStream_t stream)
{
    const float* hs = (const float*)d_in[0];
    const float* qp = (const float*)d_in[1];
    const float* kp = (const float*)d_in[2];
    const float* qb = (const float*)d_in[3];
    const float* kb = (const float*)d_in[4];

    // ws layout: hsb (8MB) | projb (4MB) | qkb (16MB) | kfrag (8MB) | red | cnt
    bf16_t* hsb   = (bf16_t*)d_ws;
    bf16_t* projb = hsb + (size_t)M_TOT * EMBED;
    bf16_t* qkb   = projb + (size_t)N_TOT * EMBED;
    bf16_t* kfrag = qkb + (size_t)M_TOT * N_TOT;
    float*  red   = (float*)(kfrag + (size_t)32 * 64 * 4 * 512);
    unsigned* cnt = (unsigned*)(red + NBLK_LSE);
    float*  out   = (float*)d_out;

    hipMemsetAsync(cnt, 0, sizeof(unsigned), stream);
    cvt_kernel<<<3072, 256, 0, stream>>>(hs, qp, kp, hsb, projb);
    proj_kernel<<<512, 256, 0, stream>>>(hsb, projb, qb, kb, qkb, kfrag);
    lse_kernel<<<NBLK_LSE, 256, 0, stream>>>(qkb, kfrag, red, cnt, out);
}